// Round 8
// baseline (343.803 us; speedup 1.0000x reference)
//
#include <hip/hip_runtime.h>
#include <math.h>

// Problem dims (from reference): B=4, C=64, T=16, H=128, W=128, fp32.
#define BB 4
#define CC 64
#define TT 16
#define HH 128
#define WW 128
#define HW (HH*WW)
#define HALO 16             // max spatial dilation
#define PW (WW + 2*HALO)    // padded LDS row stride = 160 floats
#define QROWS 32            // owned rows per block (quarter plane)
#define LROWS 64            // LDS rows = owned + 16 halo rows each side

typedef float f32x4 __attribute__((ext_vector_type(4)));

__device__ __forceinline__ float softplus_f(float x) {
    return (x > 20.0f) ? x : log1pf(expf(x));
}

// lgkm-only barrier: orders LDS traffic, leaves global loads/stores in
// flight (measured: __syncthreads' vmcnt(0) drain cost 121->140us).
__device__ __forceinline__ void barrier_lgkm() {
    asm volatile("s_waitcnt lgkmcnt(0)\n\ts_barrier" ::: "memory");
}

// 1024 blocks x 256 threads: block (sh, bc) owns rows [32*sh, 32*sh+32) of
// plane stack bc, looping t=0..15. LDS = 64 rows x 160 x 4B = 40 KB ->
// FOUR independent blocks per CU (4x40 = 160 KB; exact-full LDS proven to
// co-reside in round 6). VGPR target ~90-110 so 4 waves/SIMD x VGPR < 512
// with headroom (round 7 lesson: exact-full VGPR blocks co-residency).
// Independent blocks interleave their stage/compute phases -> HBM streams
// stay fed across barriers.
//  - temporal history (t-1, t-2) in registers (owned region only)
//  - owned AND halo rows of plane t+1 prefetched during compute(t)
//  - halo rows are sibling blocks' owned rows; bid = sh*256+bc keeps all
//    4 quarters of a stack on one XCD (bid%8==bc%8) -> halo reads L2-hit
__global__ __launch_bounds__(256, 4) void lap_st_kernel(
    const float* __restrict__ u,
    const float* __restrict__ Ds,   // (3, 64)
    const float* __restrict__ Dt,   // (2, 64)
    float* __restrict__ out)
{
    __shared__ __align__(16) float sm[LROWS * PW];   // 40960 B

    const int bid = blockIdx.x;
    const int sh  = bid >> 8;            // 0..3 : which quarter (row band)
    const int bc  = bid & 255;           // b*C + c
    const int c   = bc & (CC - 1);
    const int R0  = sh << 5;             // first owned global row
    const int tid = threadIdx.x;

    const float cs0 = softplus_f(Ds[0 * CC + c]);
    const float cs1 = softplus_f(Ds[1 * CC + c]);
    const float cs2 = softplus_f(Ds[2 * CC + c]);
    const float ct0 = softplus_f(Dt[0 * CC + c]);
    const float ct1 = softplus_f(Dt[1 * CC + c]);
    const float cu = -4.0f * (cs0 + cs1 + cs2) - (ct0 + ct1);

    const size_t bc_off = (size_t)bc * TT * HW;

    // LDS slot s holds global row clamp(R0-16+s, 0, 127).
    // Tap at global row clamp(r+/-d): slot = max(lr-d, bl) / min(lr+d, bh)
    const int bl = 16 - R0;        // clamp floor in slot space
    const int bh = 143 - R0;       // clamp ceil  in slot space

    float4 cur[4], nxt[4], pm1[4], pm2[4], hal[4];

    // ---- prologue: plane 0 owned + halo; causal clamp u[-1]=u[-2]=u[0] ----
    {
        const float* up = u + bc_off;
        #pragma unroll
        for (int i = 0; i < 4; ++i) {
            const int k  = tid + (i << 8);             // 0..1023
            const int gr = R0 + (k >> 5);              // owned global row
            cur[i] = *(const float4*)(up + gr * WW + ((k & 31) << 2));
        }
        #pragma unroll
        for (int i = 0; i < 4; ++i) {
            const int k    = tid + (i << 8);
            const int j    = k >> 5;                   // 0..31
            const int slot = (j < 16) ? j : j + 32;    // 0..15, 48..63
            int gr = R0 - 16 + slot;
            gr = (gr < 0) ? 0 : ((gr > 127) ? 127 : gr);
            hal[i] = *(const float4*)(up + gr * WW + ((k & 31) << 2));
        }
        #pragma unroll
        for (int i = 0; i < 4; ++i) { pm1[i] = cur[i]; pm2[i] = cur[i]; }
    }

    for (int t = 0; t < TT; ++t) {
        const float* up_nxt = u + bc_off + (size_t)(t + 1) * HW;
        f32x4* outp = (f32x4*)(out + bc_off + (size_t)t * HW);

        barrier_lgkm();   // prior compute's LDS reads done -> safe to overwrite

        // ---- stage owned rows (slots 16..47) with column-halo splat ----
        #pragma unroll
        for (int i = 0; i < 4; ++i) {
            const int k    = tid + (i << 8);
            const int lr   = 16 + (k >> 5);
            const int colc = k & 31;
            const float4 v = cur[i];
            *(float4*)&sm[lr * PW + HALO + (colc << 2)] = v;
            if (colc == 0) {
                float4 s = make_float4(v.x, v.x, v.x, v.x);
                float* hp = &sm[lr * PW];
                *(float4*)&hp[0] = s; *(float4*)&hp[4] = s;
                *(float4*)&hp[8] = s; *(float4*)&hp[12] = s;
            } else if (colc == 31) {
                float4 s = make_float4(v.w, v.w, v.w, v.w);
                float* hp = &sm[lr * PW + HALO + WW];
                *(float4*)&hp[0] = s; *(float4*)&hp[4] = s;
                *(float4*)&hp[8] = s; *(float4*)&hp[12] = s;
            }
        }
        // ---- stage halo rows (slots 0..15, 48..63; only vertical taps read
        //      them, always at interior columns -> no column halo needed) ----
        #pragma unroll
        for (int i = 0; i < 4; ++i) {
            const int k    = tid + (i << 8);
            const int j    = k >> 5;
            const int slot = (j < 16) ? j : j + 32;
            *(float4*)&sm[slot * PW + HALO + ((k & 31) << 2)] = hal[i];
        }

        // ---- prefetch plane t+1 (owned then halo); completes during compute ----
        if (t < TT - 1) {
            #pragma unroll
            for (int i = 0; i < 4; ++i) {
                const int k  = tid + (i << 8);
                const int gr = R0 + (k >> 5);
                nxt[i] = *(const float4*)(up_nxt + gr * WW + ((k & 31) << 2));
            }
            #pragma unroll
            for (int i = 0; i < 4; ++i) {
                const int k    = tid + (i << 8);
                const int j    = k >> 5;
                const int slot = (j < 16) ? j : j + 32;
                int gr = R0 - 16 + slot;
                gr = (gr < 0) ? 0 : ((gr > 127) ? 127 : gr);
                hal[i] = *(const float4*)(up_nxt + gr * WW + ((k & 31) << 2));
            }
        }

        barrier_lgkm();   // LDS writes visible; prefetch loads still in flight

        // ---- compute owned chunks ----
        #pragma unroll
        for (int i = 0; i < 4; ++i) {
            const int k    = tid + (i << 8);
            const int lr   = 16 + (k >> 5);     // own LDS slot
            const int colc = k & 31;
            const int col  = colc << 2;
            const float* rp = &sm[lr * PW + HALO];

            const int rU1  = (lr - 1  > bl) ? lr - 1  : bl;
            const int rD1  = (lr + 1  < bh) ? lr + 1  : bh;
            const int rU4  = (lr - 4  > bl) ? lr - 4  : bl;
            const int rD4  = (lr + 4  < bh) ? lr + 4  : bh;
            const int rU16 = (lr - 16 > bl) ? lr - 16 : bl;
            const int rD16 = (lr + 16 < bh) ? lr + 16 : bh;

            const float4 c0   = cur[i];   // center from registers
            const float4 vu1  = *(const float4*)&sm[rU1  * PW + HALO + col];
            const float4 vd1  = *(const float4*)&sm[rD1  * PW + HALO + col];
            const float4 vu4  = *(const float4*)&sm[rU4  * PW + HALO + col];
            const float4 vd4  = *(const float4*)&sm[rD4  * PW + HALO + col];
            const float4 vu16 = *(const float4*)&sm[rU16 * PW + HALO + col];
            const float4 vd16 = *(const float4*)&sm[rD16 * PW + HALO + col];
            const float4 l4   = *(const float4*)&rp[col - 4];
            const float4 r4   = *(const float4*)&rp[col + 4];
            const float4 l16  = *(const float4*)&rp[col - 16];
            const float4 r16  = *(const float4*)&rp[col + 16];

            const float4 p1 = pm1[i];
            const float4 p2 = pm2[i];

            f32x4 o;
            o.x = cs0 * (vu1.x + vd1.x + l4.w + c0.y)
                + cs1 * (vu4.x + vd4.x + l4.x + r4.x)
                + cs2 * (vu16.x + vd16.x + l16.x + r16.x)
                + cu * c0.x + ct0 * p1.x + ct1 * p2.x;
            o.y = cs0 * (vu1.y + vd1.y + c0.x + c0.z)
                + cs1 * (vu4.y + vd4.y + l4.y + r4.y)
                + cs2 * (vu16.y + vd16.y + l16.y + r16.y)
                + cu * c0.y + ct0 * p1.y + ct1 * p2.y;
            o.z = cs0 * (vu1.z + vd1.z + c0.y + c0.w)
                + cs1 * (vu4.z + vd4.z + l4.z + r4.z)
                + cs2 * (vu16.z + vd16.z + l16.z + r16.z)
                + cu * c0.z + ct0 * p1.z + ct1 * p2.z;
            o.w = cs0 * (vu1.w + vd1.w + c0.z + r4.x)
                + cs1 * (vu4.w + vd4.w + l4.w + r4.w)
                + cs2 * (vu16.w + vd16.w + l16.w + r16.w)
                + cu * c0.w + ct0 * p1.w + ct1 * p2.w;

            const int gr = R0 + (k >> 5);
            __builtin_nontemporal_store(o, &outp[gr * 32 + colc]);
        }

        // rotate temporal history; cur <- nxt is where the vmcnt wait lands
        if (t < TT - 1) {
            #pragma unroll
            for (int i = 0; i < 4; ++i) { pm2[i] = pm1[i]; pm1[i] = cur[i]; cur[i] = nxt[i]; }
        }
    }
}

extern "C" void kernel_launch(void* const* d_in, const int* in_sizes, int n_in,
                              void* d_out, int out_size, void* d_ws, size_t ws_size,
                              hipStream_t stream) {
    const float* u  = (const float*)d_in[0];
    const float* Ds = (const float*)d_in[1];
    const float* Dt = (const float*)d_in[2];
    float* out = (float*)d_out;

    const int nblocks = 4 * BB * CC;   // 1024 -> four independent blocks per CU
    lap_st_kernel<<<dim3(nblocks), dim3(256), 0, stream>>>(u, Ds, Dt, out);
}

// Round 9
// 270.053 us; speedup vs baseline: 1.2731x; 1.2731x over previous
//
#include <hip/hip_runtime.h>
#include <math.h>

// Problem dims (from reference): B=4, C=64, T=16, H=128, W=128, fp32.
#define BB 4
#define CC 64
#define TT 16
#define HH 128
#define WW 128
#define HW (HH*WW)
#define PW 128              // LDS row stride, NO column halo (128%32==0 -> clean banks)

typedef float f32x4 __attribute__((ext_vector_type(4)));

__device__ __forceinline__ float softplus_f(float x) {
    return (x > 20.0f) ? x : log1pf(expf(x));
}

// lgkm-only barrier: orders LDS traffic, leaves global loads/stores in
// flight (measured: __syncthreads' vmcnt(0) drain cost 121->140us).
__device__ __forceinline__ void barrier_lgkm() {
    asm volatile("s_waitcnt lgkmcnt(0)\n\ts_barrier" ::: "memory");
}

__device__ __forceinline__ float4 splat4(float v) { return make_float4(v, v, v, v); }

// One 1024-thread block per (b,c) plane stack (256 blocks = 1/CU), looping
// t=0..15 with PING-PONG double-buffered planes (2 x 64 KB = 128 KB LDS)
// and ONE lgkm barrier per plane:
//   barrier -> stage plane t+1 into buf[1-p] -> issue loads of t+2
//           -> compute plane t from buf[p] (+ NT store)
// LDS writes, LDS reads, HBM loads and HBM stores co-issue in one phase;
// round 5's two-barrier stage/compute lockstep idled the HBM pipes at each
// barrier (121us vs ~87us floor).
// Column halo removed: horizontal dilations are multiples of 4, so the
// replicate clamp is all-or-nothing per float4 chunk -> edge chunks become
// a splat of the row's edge element (2 broadcast b32 reads + selects).
//  - temporal history (t-1, t-2) in registers -> temporal taps free
//  - full-plane blocks: zero halo re-reads, zero fetch amplification
__global__ __launch_bounds__(1024, 4) void lap_st_kernel(
    const float* __restrict__ u,
    const float* __restrict__ Ds,   // (3, 64)
    const float* __restrict__ Dt,   // (2, 64)
    float* __restrict__ out)
{
    __shared__ __align__(16) float sm[2 * HH * PW];   // 131072 B

    const int bc  = blockIdx.x;            // b*C + c
    const int c   = bc & (CC - 1);
    const int tid = threadIdx.x;

    const float cs0 = softplus_f(Ds[0 * CC + c]);
    const float cs1 = softplus_f(Ds[1 * CC + c]);
    const float cs2 = softplus_f(Ds[2 * CC + c]);
    const float ct0 = softplus_f(Dt[0 * CC + c]);
    const float ct1 = softplus_f(Dt[1 * CC + c]);
    const float cu = -4.0f * (cs0 + cs1 + cs2) - (ct0 + ct1);

    const size_t bc_off = (size_t)bc * TT * HW;

    float4 cur[4], nxt[4], nn[4], pm1[4], pm2[4];

    // ---- prologue: plane 0 -> cur -> buf[0]; plane 1 -> nxt; clamp history ----
    {
        const float4* p0 = (const float4*)(u + bc_off);
        #pragma unroll
        for (int i = 0; i < 4; ++i) cur[i] = p0[tid + (i << 10)];
        #pragma unroll
        for (int i = 0; i < 4; ++i) {
            const int k = tid + (i << 10);
            *(float4*)&sm[(k >> 5) * PW + ((k & 31) << 2)] = cur[i];
            pm1[i] = cur[i]; pm2[i] = cur[i];   // u[-1] = u[-2] = u[0]
        }
        const float4* p1 = (const float4*)(u + bc_off + HW);
        #pragma unroll
        for (int i = 0; i < 4; ++i) nxt[i] = p1[tid + (i << 10)];
    }

    for (int t = 0; t < TT; ++t) {
        const int p = t & 1;
        float* __restrict__ smA = &sm[p * (HH * PW)];        // plane t (read)
        float* __restrict__ smB = &sm[(1 - p) * (HH * PW)];  // plane t+1 (write)
        f32x4* outp = (f32x4*)(out + bc_off + (size_t)t * HW);

        // single barrier per plane: orders (a) last iter's stage of smA
        // before this iter's reads, (b) last iter's reads of smB before
        // this iter's overwrite. Leaves global loads/stores in flight.
        barrier_lgkm();

        // ---- stage plane t+1 into smB from registers ----
        if (t < TT - 1) {
            #pragma unroll
            for (int i = 0; i < 4; ++i) {
                const int k = tid + (i << 10);
                *(float4*)&smB[(k >> 5) * PW + ((k & 31) << 2)] = nxt[i];
            }
        }

        // ---- issue loads of plane t+2 (complete during compute) ----
        if (t < TT - 2) {
            const float4* pn = (const float4*)(u + bc_off + (size_t)(t + 2) * HW);
            #pragma unroll
            for (int i = 0; i < 4; ++i) nn[i] = pn[tid + (i << 10)];
        }

        // ---- compute plane t from smA ----
        #pragma unroll
        for (int i = 0; i < 4; ++i) {
            const int k    = tid + (i << 10);
            const int row  = k >> 5;
            const int col  = (k & 31) << 2;
            const float* rp = &smA[row * PW];

            const int rU1  = (row >= 1)       ? row - 1  : 0;
            const int rD1  = (row <= HH - 2)  ? row + 1  : HH - 1;
            const int rU4  = (row >= 4)       ? row - 4  : 0;
            const int rD4  = (row <= HH - 5)  ? row + 4  : HH - 1;
            const int rU16 = (row >= 16)      ? row - 16 : 0;
            const int rD16 = (row <= HH - 17) ? row + 16 : HH - 1;

            const float4 c0   = cur[i];   // center from registers
            const float4 vu1  = *(const float4*)&smA[rU1  * PW + col];
            const float4 vd1  = *(const float4*)&smA[rD1  * PW + col];
            const float4 vu4  = *(const float4*)&smA[rU4  * PW + col];
            const float4 vd4  = *(const float4*)&smA[rD4  * PW + col];
            const float4 vu16 = *(const float4*)&smA[rU16 * PW + col];
            const float4 vd16 = *(const float4*)&smA[rD16 * PW + col];

            // horizontal taps: all-or-nothing chunk clamp (col, d mult of 4)
            const float e0   = rp[0];        // broadcast reads
            const float e127 = rp[WW - 1];
            const float4 l4r  = *(const float4*)&rp[(col >= 4)   ? col - 4  : 0];
            const float4 r4r  = *(const float4*)&rp[(col <= 120) ? col + 4  : 120];
            const float4 l16r = *(const float4*)&rp[(col >= 16)  ? col - 16 : 0];
            const float4 r16r = *(const float4*)&rp[(col <= 108) ? col + 16 : 108];
            const float4 l4  = (col >= 4)   ? l4r  : splat4(e0);
            const float4 r4  = (col <= 120) ? r4r  : splat4(e127);
            const float4 l16 = (col >= 16)  ? l16r : splat4(e0);
            const float4 r16 = (col <= 108) ? r16r : splat4(e127);

            const float4 p1 = pm1[i];
            const float4 p2 = pm2[i];

            f32x4 o;
            o.x = cs0 * (vu1.x + vd1.x + l4.w + c0.y)
                + cs1 * (vu4.x + vd4.x + l4.x + r4.x)
                + cs2 * (vu16.x + vd16.x + l16.x + r16.x)
                + cu * c0.x + ct0 * p1.x + ct1 * p2.x;
            o.y = cs0 * (vu1.y + vd1.y + c0.x + c0.z)
                + cs1 * (vu4.y + vd4.y + l4.y + r4.y)
                + cs2 * (vu16.y + vd16.y + l16.y + r16.y)
                + cu * c0.y + ct0 * p1.y + ct1 * p2.y;
            o.z = cs0 * (vu1.z + vd1.z + c0.y + c0.w)
                + cs1 * (vu4.z + vd4.z + l4.z + r4.z)
                + cs2 * (vu16.z + vd16.z + l16.z + r16.z)
                + cu * c0.z + ct0 * p1.z + ct1 * p2.z;
            o.w = cs0 * (vu1.w + vd1.w + c0.z + r4.x)
                + cs1 * (vu4.w + vd4.w + l4.w + r4.w)
                + cs2 * (vu16.w + vd16.w + l16.w + r16.w)
                + cu * c0.w + ct0 * p1.w + ct1 * p2.w;

            __builtin_nontemporal_store(o, &outp[k]);   // streaming, never re-read
        }

        // rotate temporal history; cur<-nxt, nxt<-nn (vmcnt wait lands here)
        if (t < TT - 1) {
            #pragma unroll
            for (int i = 0; i < 4; ++i) {
                pm2[i] = pm1[i]; pm1[i] = cur[i]; cur[i] = nxt[i]; nxt[i] = nn[i];
            }
        }
    }
}

extern "C" void kernel_launch(void* const* d_in, const int* in_sizes, int n_in,
                              void* d_out, int out_size, void* d_ws, size_t ws_size,
                              hipStream_t stream) {
    const float* u  = (const float*)d_in[0];
    const float* Ds = (const float*)d_in[1];
    const float* Dt = (const float*)d_in[2];
    float* out = (float*)d_out;

    const int nblocks = BB * CC;   // 256 -> one block per CU
    lap_st_kernel<<<dim3(nblocks), dim3(1024), 0, stream>>>(u, Ds, Dt, out);
}

// Round 10
// 113.397 us; speedup vs baseline: 3.0318x; 2.3815x over previous
//
#include <hip/hip_runtime.h>
#include <math.h>

// Problem dims (from reference): B=4, C=64, T=16, H=128, W=128, fp32.
#define BB 4
#define CC 64
#define TT 16
#define HH 128
#define WW 128
#define HW (HH*WW)

typedef float f32x4 __attribute__((ext_vector_type(4)));

__device__ __forceinline__ float softplus_f(float x) {
    return (x > 20.0f) ? x : log1pf(expf(x));
}

__device__ __forceinline__ float4 splat4(float v) { return make_float4(v, v, v, v); }

// Pure cache-tap stencil: NO LDS, NO barriers. 1024 blocks x 256 threads;
// block (sh, bc) owns rows [32*sh, 32*sh+32) of plane stack bc for all t.
// Every spatial tap is a direct global load served by L1/L2 (plane = 64 KB
// << 4 MB L2/XCD; all 4 bands of a stack share an XCD since bid%8 == bc%8;
// L2 misses land in L3, never HBM) -> HBM stays at the 537 MB minimum with
// zero read amplification.  Waves free-run: no barrier drains, no LDS
// lockstep (every LDS variant plateaued at >=121us), latency hidden by
// ~48 in-flight VMEM ops per thread.
//  - thread owns 4 STACKED rows (r0..r0+3): +-1 vertical taps come from its
//    own center registers; only 16 neighbor-row loads + 16 horizontal loads
//  - temporal history (t-1, t-2) in registers (thread owns fixed rows)
//  - horizontal replicate clamp: all-or-nothing per float4 chunk (dilations
//    4,16 are chunk-aligned; d=1 via intra/inter-chunk element shifts)
//  - plain __launch_bounds__(256): the ",N" min-waves variants pinned
//    VGPR=64 and spilled (rounds 6,8,9: FETCH/WRITE inflated by scratch)
__global__ __launch_bounds__(256) void lap_st_kernel(
    const float* __restrict__ u,
    const float* __restrict__ Ds,   // (3, 64)
    const float* __restrict__ Dt,   // (2, 64)
    float* __restrict__ out)
{
    const int bid  = blockIdx.x;
    const int sh   = bid >> 8;             // 0..3 : row band
    const int bc   = bid & 255;            // b*C + c
    const int c    = bc & (CC - 1);
    const int tid  = threadIdx.x;
    const int jj   = tid >> 5;             // 0..7 : row group within band
    const int colc = tid & 31;             // chunk column
    const int col  = colc << 2;
    const int r0   = (sh << 5) + (jj << 2); // first of 4 owned rows, 0..124

    const float cs0 = softplus_f(Ds[0 * CC + c]);
    const float cs1 = softplus_f(Ds[1 * CC + c]);
    const float cs2 = softplus_f(Ds[2 * CC + c]);
    const float ct0 = softplus_f(Dt[0 * CC + c]);
    const float ct1 = softplus_f(Dt[1 * CC + c]);
    const float cu = -4.0f * (cs0 + cs1 + cs2) - (ct0 + ct1);

    const size_t bc_off = (size_t)bc * TT * HW;

    float4 pm1[4], pm2[4];

    #pragma unroll 1
    for (int t = 0; t < TT; ++t) {
        const float* __restrict__ up = u + bc_off + (size_t)t * HW;
        f32x4* outp = (f32x4*)(out + bc_off + (size_t)t * HW);

        // center rows (kept in registers; feed +-1 taps and temporal rotate)
        float4 c0[4];
        #pragma unroll
        for (int q = 0; q < 4; ++q)
            c0[q] = *(const float4*)(up + (r0 + q) * WW + col);

        if (t == 0) {   // causal clamp: u[-1] = u[-2] = u[0]
            #pragma unroll
            for (int q = 0; q < 4; ++q) { pm1[q] = c0[q]; pm2[q] = c0[q]; }
        }

        // shared boundary rows (serve +-1 taps of edge q and +-4 taps)
        const int rm1 = (r0 - 1 < 0) ? 0 : r0 - 1;
        const int rp4 = (r0 + 4 > HH - 1) ? HH - 1 : r0 + 4;
        const float4 vm1 = *(const float4*)(up + rm1 * WW + col);
        const float4 vp4 = *(const float4*)(up + rp4 * WW + col);

        #pragma unroll
        for (int q = 0; q < 4; ++q) {
            const int r = r0 + q;

            // ---- vertical taps (register reuse for d=1; clamped loads) ----
            const float4 vu1 = (q == 0) ? vm1 : c0[q - 1];
            const float4 vd1 = (q == 3) ? vp4 : c0[q + 1];
            float4 vu4, vd4;
            if (q == 3) vu4 = vm1;                       // r+(-4) == r0-1
            else { int rr = r - 4; rr = rr < 0 ? 0 : rr;
                   vu4 = *(const float4*)(up + rr * WW + col); }
            if (q == 0) vd4 = vp4;                       // r+4 == r0+4
            else { int rr = r + 4; rr = rr > HH - 1 ? HH - 1 : rr;
                   vd4 = *(const float4*)(up + rr * WW + col); }
            int ru16 = r - 16; ru16 = ru16 < 0 ? 0 : ru16;
            int rd16 = r + 16; rd16 = rd16 > HH - 1 ? HH - 1 : rd16;
            const float4 vu16 = *(const float4*)(up + ru16 * WW + col);
            const float4 vd16 = *(const float4*)(up + rd16 * WW + col);

            // ---- horizontal taps (all-or-nothing chunk clamp + edge splat) ----
            const float* rp = up + r * WW;
            const float e0   = rp[0];
            const float e127 = rp[WW - 1];
            const float4 l4r  = *(const float4*)(rp + ((colc >= 1)  ? col - 4  : 0));
            const float4 r4r  = *(const float4*)(rp + ((colc <= 30) ? col + 4  : 124));
            const float4 l16r = *(const float4*)(rp + ((colc >= 4)  ? col - 16 : 0));
            const float4 r16r = *(const float4*)(rp + ((colc <= 27) ? col + 16 : 112));
            const float4 l4  = (colc >= 1)  ? l4r  : splat4(e0);
            const float4 r4  = (colc <= 30) ? r4r  : splat4(e127);
            const float4 l16 = (colc >= 4)  ? l16r : splat4(e0);
            const float4 r16 = (colc <= 27) ? r16r : splat4(e127);

            const float4 cc = c0[q];
            const float4 p1 = pm1[q];
            const float4 p2 = pm2[q];

            f32x4 o;
            o.x = cs0 * (vu1.x + vd1.x + l4.w + cc.y)
                + cs1 * (vu4.x + vd4.x + l4.x + r4.x)
                + cs2 * (vu16.x + vd16.x + l16.x + r16.x)
                + cu * cc.x + ct0 * p1.x + ct1 * p2.x;
            o.y = cs0 * (vu1.y + vd1.y + cc.x + cc.z)
                + cs1 * (vu4.y + vd4.y + l4.y + r4.y)
                + cs2 * (vu16.y + vd16.y + l16.y + r16.y)
                + cu * cc.y + ct0 * p1.y + ct1 * p2.y;
            o.z = cs0 * (vu1.z + vd1.z + cc.y + cc.w)
                + cs1 * (vu4.z + vd4.z + l4.z + r4.z)
                + cs2 * (vu16.z + vd16.z + l16.z + r16.z)
                + cu * cc.z + ct0 * p1.z + ct1 * p2.z;
            o.w = cs0 * (vu1.w + vd1.w + cc.z + r4.x)
                + cs1 * (vu4.w + vd4.w + l4.w + r4.w)
                + cs2 * (vu16.w + vd16.w + l16.w + r16.w)
                + cu * cc.w + ct0 * p1.w + ct1 * p2.w;

            __builtin_nontemporal_store(o, &outp[r * 32 + colc]);
        }

        // rotate temporal history
        #pragma unroll
        for (int q = 0; q < 4; ++q) { pm2[q] = pm1[q]; pm1[q] = c0[q]; }
    }
}

extern "C" void kernel_launch(void* const* d_in, const int* in_sizes, int n_in,
                              void* d_out, int out_size, void* d_ws, size_t ws_size,
                              hipStream_t stream) {
    const float* u  = (const float*)d_in[0];
    const float* Ds = (const float*)d_in[1];
    const float* Dt = (const float*)d_in[2];
    float* out = (float*)d_out;

    const int nblocks = 4 * BB * CC;   // 1024 blocks = 4 independent per CU
    lap_st_kernel<<<dim3(nblocks), dim3(256), 0, stream>>>(u, Ds, Dt, out);
}

// Round 11
// 101.217 us; speedup vs baseline: 3.3967x; 1.1203x over previous
//
#include <hip/hip_runtime.h>
#include <math.h>

// Problem dims (from reference): B=4, C=64, T=16, H=128, W=128, fp32.
#define BB 4
#define CC 64
#define TT 16
#define HH 128
#define WW 128
#define HW (HH*WW)

typedef float f32x4 __attribute__((ext_vector_type(4)));

__device__ __forceinline__ float softplus_f(float x) {
    return (x > 20.0f) ? x : log1pf(expf(x));
}

__device__ __forceinline__ float4 splat4(float v) { return make_float4(v, v, v, v); }

// float4 cross-lane fetch within a 32-lane row segment (ds_bpermute x4).
// Out-of-range src wraps (&31) -> caller masks those lanes with a select.
__device__ __forceinline__ float4 shfl4(float4 v, int src) {
    float4 r;
    r.x = __shfl(v.x, src, 32);
    r.y = __shfl(v.y, src, 32);
    r.z = __shfl(v.z, src, 32);
    r.w = __shfl(v.w, src, 32);
    return r;
}

// Pure cache-tap stencil, round-10 structure (113us) + horizontal taps via
// LANE SHUFFLES instead of loads. A 32-lane half-wave covers one full row
// (32 float4 chunks), so chunk colc-1/+1/-4/+4 lives in lane-1/+1/-4/+4's
// center register: l4/r4/l16/r16 + e0/e127 become ds_bpermute (LDS pipe,
// idle) instead of 24 of the 44 VMEM loads -> L1/L2 read traffic -55%
// (2.95 GB -> 1.34 GB; round-10 was running ~26 TB/s against the ~34.5
// TB/s L2 ceiling).
//  - NO LDS buffers, NO barriers: waves free-run (every LDS-lockstep
//    variant plateaued >= 121us)
//  - 1024 blocks x 256 threads; block (sh,bc) owns rows [32sh,32sh+32) of
//    stack bc for all t; bid%8==bc%8 keeps a stack's 4 bands on one XCD
//  - thread owns 4 stacked rows: vertical d=1 taps from own registers
//  - temporal history (t-1,t-2) in registers -> temporal taps free
//  - plain __launch_bounds__(256): ",N" variants pinned VGPR=64 and
//    spilled (rounds 6/8/9)
__global__ __launch_bounds__(256) void lap_st_kernel(
    const float* __restrict__ u,
    const float* __restrict__ Ds,   // (3, 64)
    const float* __restrict__ Dt,   // (2, 64)
    float* __restrict__ out)
{
    const int bid  = blockIdx.x;
    const int sh   = bid >> 8;             // 0..3 : row band
    const int bc   = bid & 255;            // b*C + c
    const int c    = bc & (CC - 1);
    const int tid  = threadIdx.x;
    const int jj   = tid >> 5;             // 0..7 : row group within band
    const int colc = tid & 31;             // chunk column (lane in row segment)
    const int col  = colc << 2;
    const int r0   = (sh << 5) + (jj << 2); // first of 4 owned rows, 0..124

    const float cs0 = softplus_f(Ds[0 * CC + c]);
    const float cs1 = softplus_f(Ds[1 * CC + c]);
    const float cs2 = softplus_f(Ds[2 * CC + c]);
    const float ct0 = softplus_f(Dt[0 * CC + c]);
    const float ct1 = softplus_f(Dt[1 * CC + c]);
    const float cu = -4.0f * (cs0 + cs1 + cs2) - (ct0 + ct1);

    const size_t bc_off = (size_t)bc * TT * HW;

    float4 pm1[4], pm2[4];

    #pragma unroll 1
    for (int t = 0; t < TT; ++t) {
        const float* __restrict__ up = u + bc_off + (size_t)t * HW;
        f32x4* outp = (f32x4*)(out + bc_off + (size_t)t * HW);

        // center rows (registers; feed +-1 taps, horizontals via shuffle,
        // and the temporal rotate)
        float4 c0[4];
        #pragma unroll
        for (int q = 0; q < 4; ++q)
            c0[q] = *(const float4*)(up + (r0 + q) * WW + col);

        if (t == 0) {   // causal clamp: u[-1] = u[-2] = u[0]
            #pragma unroll
            for (int q = 0; q < 4; ++q) { pm1[q] = c0[q]; pm2[q] = c0[q]; }
        }

        // shared boundary rows (serve +-1 taps of edge q and +-4 taps)
        const int rm1 = (r0 - 1 < 0) ? 0 : r0 - 1;
        const int rp4 = (r0 + 4 > HH - 1) ? HH - 1 : r0 + 4;
        const float4 vm1 = *(const float4*)(up + rm1 * WW + col);
        const float4 vp4 = *(const float4*)(up + rp4 * WW + col);

        #pragma unroll
        for (int q = 0; q < 4; ++q) {
            const int r = r0 + q;

            // ---- vertical taps (register reuse for d=1; clamped loads) ----
            const float4 vu1 = (q == 0) ? vm1 : c0[q - 1];
            const float4 vd1 = (q == 3) ? vp4 : c0[q + 1];
            float4 vu4, vd4;
            if (q == 3) vu4 = vm1;                       // r-4 == r0-1
            else { int rr = r - 4; rr = rr < 0 ? 0 : rr;
                   vu4 = *(const float4*)(up + rr * WW + col); }
            if (q == 0) vd4 = vp4;                       // r+4 == r0+4
            else { int rr = r + 4; rr = rr > HH - 1 ? HH - 1 : rr;
                   vd4 = *(const float4*)(up + rr * WW + col); }
            int ru16 = r - 16; ru16 = ru16 < 0 ? 0 : ru16;
            int rd16 = r + 16; rd16 = rd16 > HH - 1 ? HH - 1 : rd16;
            const float4 vu16 = *(const float4*)(up + ru16 * WW + col);
            const float4 vd16 = *(const float4*)(up + rd16 * WW + col);

            const float4 cc = c0[q];

            // ---- horizontal taps from adjacent lanes' registers ----
            const float4 L4  = shfl4(cc, colc - 1);
            const float4 R4  = shfl4(cc, colc + 1);
            const float4 L16 = shfl4(cc, colc - 4);
            const float4 R16 = shfl4(cc, colc + 4);
            const float e0   = __shfl(cc.x, 0, 32);    // row elem 0
            const float e127 = __shfl(cc.w, 31, 32);   // row elem 127
            const float4 l4  = (colc >= 1)  ? L4  : splat4(e0);
            const float4 r4  = (colc <= 30) ? R4  : splat4(e127);
            const float4 l16 = (colc >= 4)  ? L16 : splat4(e0);
            const float4 r16 = (colc <= 27) ? R16 : splat4(e127);

            const float4 p1 = pm1[q];
            const float4 p2 = pm2[q];

            f32x4 o;
            o.x = cs0 * (vu1.x + vd1.x + l4.w + cc.y)
                + cs1 * (vu4.x + vd4.x + l4.x + r4.x)
                + cs2 * (vu16.x + vd16.x + l16.x + r16.x)
                + cu * cc.x + ct0 * p1.x + ct1 * p2.x;
            o.y = cs0 * (vu1.y + vd1.y + cc.x + cc.z)
                + cs1 * (vu4.y + vd4.y + l4.y + r4.y)
                + cs2 * (vu16.y + vd16.y + l16.y + r16.y)
                + cu * cc.y + ct0 * p1.y + ct1 * p2.y;
            o.z = cs0 * (vu1.z + vd1.z + cc.y + cc.w)
                + cs1 * (vu4.z + vd4.z + l4.z + r4.z)
                + cs2 * (vu16.z + vd16.z + l16.z + r16.z)
                + cu * cc.z + ct0 * p1.z + ct1 * p2.z;
            o.w = cs0 * (vu1.w + vd1.w + cc.z + r4.x)
                + cs1 * (vu4.w + vd4.w + l4.w + r4.w)
                + cs2 * (vu16.w + vd16.w + l16.w + r16.w)
                + cu * cc.w + ct0 * p1.w + ct1 * p2.w;

            __builtin_nontemporal_store(o, &outp[r * 32 + colc]);
        }

        // rotate temporal history
        #pragma unroll
        for (int q = 0; q < 4; ++q) { pm2[q] = pm1[q]; pm1[q] = c0[q]; }
    }
}

extern "C" void kernel_launch(void* const* d_in, const int* in_sizes, int n_in,
                              void* d_out, int out_size, void* d_ws, size_t ws_size,
                              hipStream_t stream) {
    const float* u  = (const float*)d_in[0];
    const float* Ds = (const float*)d_in[1];
    const float* Dt = (const float*)d_in[2];
    float* out = (float*)d_out;

    const int nblocks = 4 * BB * CC;   // 1024 blocks = 4 independent per CU
    lap_st_kernel<<<dim3(nblocks), dim3(256), 0, stream>>>(u, Ds, Dt, out);
}